// Round 13
// baseline (123.079 us; speedup 1.0000x reference)
//
#include <hip/hip_runtime.h>
#include <hip/hip_bf16.h>
#include <math.h>

// CerberusSemanticIDBranch — fused prototype-softmax-affinity kernel for MI355X.
//
// out[r,g,:] = (e_g @ M'_g) / sum(e_g),  e_k = exp(l_k - max_g),
// l_k = (x_r . Pn_k) / ((||x_r||+1e-6) * tau),  Pn_k = P_k/(||P_k||+1e-6),
// M'_g = A_g @ P_g / (rowsum(A_g)+1e-6)   (rowsum(A) is constant per group).
//
// Round 13: attack DRAM page locality of the 335 MB store stream. Previous
// phase 2 stored 256B chunks at 10KB row stride (a page-activate per chunk;
// ~3.8 TB/s effective vs fillBuffer's 6.9 linear). Now phase 2 runs 10
// sub-rounds (slab x group): the slab's waves compute their swapped-MFMA
// tiles into a 16x516 LDS tile (33 KB, aliases dead lred), then ALL threads
// sweep-store it in address order — every instr covers 2 rows x 2KB
// contiguous (1KB contiguous per wave), rows walked sequentially. 2KB DRAM
// bursts instead of 256B. 4 blocks/CU preserved.

constexpr int D    = 512;
constexpr int KTOT = 121;
constexpr float TAU = 0.07f;

constexpr int GB[5]  = {0, 2, 17, 57, 97};   // group base row in concat [121] layout
constexpr int GK[5]  = {2, 15, 40, 40, 24};  // prototypes per group
constexpr int GD2[5] = {1, 3, 5, 5, 4};      // second attribute cardinality
constexpr int GNA[5] = {1, 2, 2, 2, 2};      // number of attributes
constexpr int KS0[5] = {0, 0, 0, 1, 3};      // first live 32-wide kstep of group
constexpr int KS1[5] = {1, 1, 2, 4, 4};      // one past last live kstep

constexpr int BSTRIDE = 516;                 // buf row stride (16B-aligned, odd mod 32 words)

using f32x4 = __attribute__((ext_vector_type(4))) float;
using s16x8 = __attribute__((ext_vector_type(8))) short;

__device__ __forceinline__ const float* pick(int k,
    const float* P0, const float* P1, const float* P2, const float* P3, const float* P4,
    int* kl) {
  if (k < 2)  { *kl = k;      return P0; }
  if (k < 17) { *kl = k - 2;  return P1; }
  if (k < 57) { *kl = k - 17; return P2; }
  if (k < 97) { *kl = k - 57; return P3; }
  *kl = k - 97; return P4;
}

__device__ __forceinline__ short f2bf(float f) {
  __hip_bfloat16 h = __float2bfloat16(f);   // RTNE
  return *reinterpret_cast<short*>(&h);
}

// ---- merged prep kernel -------------------------------------------------
// Blocks 0..7   (ct): pnbf 16-col slab — compute the 16 prototype-row norms
//                     in-block, then write the 16 fragment-linear s-blocks.
// Blocks 8..647 (c2): one 512-u16 fragment-linear block of mptbf.
// pnbf[(ct*16+s)*512 + lane*8 + j] = Pn[ct*16+(lane&15)][s*32+(lane>>4)*8+j]
// mptbf[(c*4+ks)*512 + lane*8 + j] = Mtilde[ks*32+(lane>>4)*8+j][c*16+(lane&15)]
__global__ __launch_bounds__(256) void prep_all(
    const float* __restrict__ P0, const float* __restrict__ P1,
    const float* __restrict__ P2, const float* __restrict__ P3,
    const float* __restrict__ P4, unsigned short* __restrict__ pnbf,
    unsigned short* __restrict__ mptbf) {
  const int tid = threadIdx.x;
  if (blockIdx.x < 8) {
    const int ct = blockIdx.x;
    __shared__ float lsum[16][17];
    __shared__ float linv[16];
    {
      const int i = tid >> 4, part = tid & 15;
      const int col = ct * 16 + i;
      float s = 0.f;
      if (col < KTOT) {
        int kl; const float* P = pick(col, P0, P1, P2, P3, P4, &kl);
        const float* row = P + (size_t)kl * D + part * 32;
        #pragma unroll
        for (int e = 0; e < 32; ++e) { float v = row[e]; s += v * v; }
      }
      lsum[i][part] = s;
    }
    __syncthreads();
    if (tid < 16) {
      float s = 0.f;
      #pragma unroll
      for (int p = 0; p < 16; ++p) s += lsum[tid][p];
      linv[tid] = 1.f / (sqrtf(s) + 1e-6f);
    }
    __syncthreads();
    for (int s = 0; s < 16; ++s) {
      #pragma unroll
      for (int half = 0; half < 2; ++half) {
        const int e = tid + half * 256;
        const int lane = e >> 3, j = e & 7;
        const int col = ct * 16 + (lane & 15);
        const int k   = s * 32 + (lane >> 4) * 8 + j;
        float v = 0.f;
        if (col < KTOT) {
          int kl; const float* P = pick(col, P0, P1, P2, P3, P4, &kl);
          v = P[(size_t)kl * D + k] * linv[lane & 15];
        }
        pnbf[(size_t)(ct * 16 + s) * 512 + e] = (unsigned short)f2bf(v);
      }
    }
  } else {
    const int c2 = blockIdx.x - 8;           // 0..639
    const int c = c2 >> 2, ks = c2 & 3;
    #pragma unroll
    for (int half = 0; half < 2; ++half) {
      const int e = tid + half * 256;
      const int lane = e >> 3, j = e & 7;
      const int gd = c * 16 + (lane & 15);
      const int k  = ks * 32 + (lane >> 4) * 8 + j;
      const int g = gd >> 9, d = gd & (D - 1);
      float v = 0.f;
      if (k >= GB[g] && k < GB[g] + GK[g]) {
        int kl = k - GB[g];
        const float* P = (g == 0) ? P0 : (g == 1) ? P1 : (g == 2) ? P2 : (g == 3) ? P3 : P4;
        int d2 = GD2[g], na = GNA[g], K = GK[g];
        int a1 = kl / d2, a2 = kl % d2;
        float s = 0.f, m = 0.f;
        for (int jj = 0; jj < K; jj++) {
          float aff;
          if (na == 1) {
            aff = (jj == kl) ? 1.f : 0.f;
          } else {
            int b1 = jj / d2, b2 = jj % d2;
            aff = 0.5f * (float)((a1 == b1) + (a2 == b2));
          }
          s += aff;
          m += aff * P[(size_t)jj * D + d];
        }
        v = m / (s + 1e-6f);
      }
      mptbf[(size_t)c2 * 512 + e] = (unsigned short)f2bf(v);
    }
  }
}

// ---- phase 2 fill: compute one (slab, G) 16x512 tile into LDS buf -------
// Wave handles 4 strips (64 within-group cols each): sloc = i*2 + ch.
// SWAPPED mfma: lane holds out row l15, within-strip cols 16t+4hi+reg.
template <int G>
__device__ __forceinline__ void phase2_fill(
    const s16x8 (&af2)[4], const unsigned short* __restrict__ mptbf,
    float* __restrict__ buf, int ch, int lane) {
  const int l15 = lane & 15, hi = lane >> 4;
  #pragma unroll 1
  for (int i = 0; i < 4; ++i) {
    const int sloc = i * 2 + ch;               // within-group strip 0..7
    const int s    = G * 8 + sloc;             // global strip
    const unsigned short* bp = mptbf + (size_t)(s * 4) * 4 * 512 + lane * 8;
    f32x4 a0 = (f32x4){0.f, 0.f, 0.f, 0.f}, a1 = a0, a2 = a0, a3 = a0;
    #pragma unroll
    for (int ks = KS0[G]; ks < KS1[G]; ++ks) {  // constexpr -> af2[ks] static
      s16x8 b0 = *(const s16x8*)(bp + (0 * 4 + ks) * 512);
      s16x8 b1 = *(const s16x8*)(bp + (1 * 4 + ks) * 512);
      s16x8 b2 = *(const s16x8*)(bp + (2 * 4 + ks) * 512);
      s16x8 b3 = *(const s16x8*)(bp + (3 * 4 + ks) * 512);
      a0 = __builtin_amdgcn_mfma_f32_16x16x32_bf16(b0, af2[ks], a0, 0, 0, 0);
      a1 = __builtin_amdgcn_mfma_f32_16x16x32_bf16(b1, af2[ks], a1, 0, 0, 0);
      a2 = __builtin_amdgcn_mfma_f32_16x16x32_bf16(b2, af2[ks], a2, 0, 0, 0);
      a3 = __builtin_amdgcn_mfma_f32_16x16x32_bf16(b3, af2[ks], a3, 0, 0, 0);
    }
    float* bb = buf + l15 * BSTRIDE + sloc * 64 + hi * 4;
    *(f32x4*)(bb +  0) = a0;
    *(f32x4*)(bb + 16) = a1;
    *(f32x4*)(bb + 32) = a2;
    *(f32x4*)(bb + 48) = a3;
  }
}

// ---- phase 2 sweep: store buf[16][512] in address order -----------------
// 256 threads: per instr 2 rows x 2KB contiguous (per wave: 1KB contiguous).
__device__ __forceinline__ void sweep_store(
    const float* __restrict__ buf, float* __restrict__ gb,
    int swrow, int swcol) {
  #pragma unroll
  for (int it = 0; it < 8; ++it) {
    const int row = it * 2 + swrow;
    f32x4 v = *(const f32x4*)(buf + row * BSTRIDE + swcol);
    *(f32x4*)(gb + (size_t)row * 2560 + swcol) = v;
  }
}

// ---- main fused kernel --------------------------------------------------
// 1024 blocks x 256 threads (4 waves); block owns 32 rows. Phase 1: wave
// slab = w&1 (16 rows), ch = w>>1 (64-col half), 16 ksteps x 4 MFMA.
// Phase 2: 10 sub-rounds (slab x group) of fill + linear sweep.
__global__ __launch_bounds__(256, 4) void fused_main(
    const float* __restrict__ x, const unsigned short* __restrict__ pnbf,
    const unsigned short* __restrict__ mptbf, float* __restrict__ out) {
  // smem: lred[128][33] (4224 f32) for phases 1/softmax/A-build, then
  // buf[16][516] (8256 f32 = 33 KB) for the phase-2 staged stores.
  __shared__ __align__(16) float smem[8256];
  __shared__ float xsqs[32];
  float (*lred)[33] = (float (*)[33])smem;

  const int tid  = threadIdx.x;
  const int lane = tid & 63;
  const int w    = __builtin_amdgcn_readfirstlane(tid >> 6);
  const int r0   = blockIdx.x * 32;

  const int wr = (w & 1) << 4;   // wave's 16-row slab (block-local)
  const int ch = w >> 1;         // column half / strip parity
  const int ko = (lane >> 4) << 3;

  // ---- phase 1: 16x64 logit tile via MFMA, K = 512 ----
  {
    const int arow = wr + (lane & 15);
    const float* xrow = x + (size_t)(r0 + arow) * D + ko;

    f32x4 acc[4];
    #pragma unroll
    for (int t = 0; t < 4; ++t) acc[t] = (f32x4){0.f, 0.f, 0.f, 0.f};
    float xsq = 0.f;

    #pragma unroll 4
    for (int s = 0; s < 16; ++s) {
      float4 a0 = *(const float4*)(xrow + s * 32);
      float4 a1 = *(const float4*)(xrow + s * 32 + 4);
      xsq += a0.x * a0.x + a0.y * a0.y + a0.z * a0.z + a0.w * a0.w
           + a1.x * a1.x + a1.y * a1.y + a1.z * a1.z + a1.w * a1.w;
      s16x8 af;
      af[0] = f2bf(a0.x); af[1] = f2bf(a0.y); af[2] = f2bf(a0.z); af[3] = f2bf(a0.w);
      af[4] = f2bf(a1.x); af[5] = f2bf(a1.y); af[6] = f2bf(a1.z); af[7] = f2bf(a1.w);
      #pragma unroll
      for (int t = 0; t < 4; ++t) {
        // fragment-linear B: one contiguous 1KB wave load
        s16x8 bfv = *(const s16x8*)(pnbf + (size_t)(((ch << 2) + t) * 16 + s) * 512 + lane * 8);
        acc[t] = __builtin_amdgcn_mfma_f32_16x16x32_bf16(af, bfv, acc[t], 0, 0, 0);
      }
    }

    // ||x||^2: lanes {l, l^16, l^32, l^48} share the same A-row
    xsq += __shfl_xor(xsq, 16);
    xsq += __shfl_xor(xsq, 32);
    if (ch == 0 && lane < 16) xsqs[wr + lane] = xsq;

    // dump C-frags: col = lane&15, row = (lane>>4)*4 + j
    const int drow = wr + ((lane >> 4) << 2);
    #pragma unroll
    for (int t = 0; t < 4; ++t) {
      const int col = (ch << 6) + (t << 4) + (lane & 15);
      #pragma unroll
      for (int j = 0; j < 4; ++j) lred[col][drow + j] = acc[t][j];
    }
  }
  __syncthreads();

  // ---- softmax (lane = row, 32 rows): w0 -> g0,g4; w1 -> g1; w2 -> g2;
  // w3 -> g3 (3-pass in LDS) ----
  if (lane < 32) {
    const float scale = 1.f / ((sqrtf(xsqs[lane]) + 1e-6f) * TAU);
    const int gfirst = (w == 0) ? 0 : w;
    const int glast  = (w == 0) ? 4 : w;     // w0 does 0 then 4
    for (int g = gfirst; g <= glast; g += (w == 0) ? 4 : 1) {
      float mx = -1e30f;
      for (int kk = 0; kk < GK[g]; ++kk)
        mx = fmaxf(mx, lred[GB[g] + kk][lane]);
      float E = 0.f;
      for (int kk = 0; kk < GK[g]; ++kk) {
        float e = __expf((lred[GB[g] + kk][lane] - mx) * scale);
        lred[GB[g] + kk][lane] = e;
        E += e;
      }
      const float inv = 1.f / E;
      for (int kk = 0; kk < GK[g]; ++kk) lred[GB[g] + kk][lane] *= inv;
    }
  }
  __syncthreads();

  // ---- A-frags for phase 2 (c as MFMA B-operand; lred still live) ----
  s16x8 af2[4];
  {
    const int ar = wr + (lane & 15);
    #pragma unroll
    for (int s = 0; s < 4; ++s) {
      const int kbase = s * 32 + ko;
      s16x8 f;
      #pragma unroll
      for (int j = 0; j < 8; ++j) f[j] = f2bf(lred[kbase + j][ar]);
      af2[s] = f;
    }
  }
  __syncthreads();   // lred dead; smem becomes the staged-store buf

  // ---- phase 2: 10 sub-rounds (slab x group): fill tile, linear sweep ----
  {
    float* buf = smem;
    const int swrow = tid >> 7;           // 0/1
    const int swcol = (tid & 127) * 4;    // 0..508

#define SUBROUND(SLAB2, G)                                                    \
    if ((w & 1) == (SLAB2)) phase2_fill<G>(af2, mptbf, buf, ch, lane);        \
    __syncthreads();                                                          \
    sweep_store(buf, out + (size_t)(r0 + (SLAB2) * 16) * 2560 + (G) * 512,    \
                swrow, swcol);                                                \
    __syncthreads();

    SUBROUND(0, 0) SUBROUND(0, 1) SUBROUND(0, 2) SUBROUND(0, 3) SUBROUND(0, 4)
    SUBROUND(1, 0) SUBROUND(1, 1) SUBROUND(1, 2) SUBROUND(1, 3) SUBROUND(1, 4)
#undef SUBROUND
  }
}

extern "C" void kernel_launch(void* const* d_in, const int* in_sizes, int n_in,
                              void* d_out, int out_size, void* d_ws, size_t ws_size,
                              hipStream_t stream) {
  const float* x  = (const float*)d_in[0];
  const float* P0 = (const float*)d_in[1];  // gender [2,512]
  const float* P1 = (const float*)d_in[2];  // hair   [15,512]
  const float* P2 = (const float*)d_in[3];  // top    [40,512]
  const float* P3 = (const float*)d_in[4];  // pants  [40,512]
  const float* P4 = (const float*)d_in[5];  // shoes  [24,512]
  float* out = (float*)d_out;

  unsigned short* pnbf  = (unsigned short*)d_ws;       // 128*512  u16 = 128 KiB
  unsigned short* mptbf = pnbf + 128 * 512;            // 640*512  u16 = 640 KiB

  prep_all<<<dim3(648), dim3(256), 0, stream>>>(P0, P1, P2, P3, P4, pnbf, mptbf);
  fused_main<<<dim3(1024), dim3(256), 0, stream>>>(x, pnbf, mptbf, out);
}

// Round 14
// 115.992 us; speedup vs baseline: 1.0611x; 1.0611x over previous
//
#include <hip/hip_runtime.h>
#include <hip/hip_bf16.h>
#include <math.h>

// CerberusSemanticIDBranch — fused prototype-softmax-affinity kernel for MI355X.
//
// out[r,g,:] = (e_g @ M'_g) / sum(e_g),  e_k = exp(l_k - max_g),
// l_k = (x_r . Pn_k) / ((||x_r||+1e-6) * tau),  Pn_k = P_k/(||P_k||+1e-6),
// M'_g = A_g @ P_g / (rowsum(A_g)+1e-6)   (rowsum(A) is constant per group).
//
// Round 14 = round 12 (best: 116us) + phase-2 store/load vmcnt decoupling.
// CDNA stores and loads share vmcnt; r12's strip loop (unroll 1) issued
// loads AFTER the previous strip's stores, so the compiler's vmcnt(3) wait
// for the loads could only be satisfied after all older stores were ack'd
// by the (saturated) memory system -> every strip serialized on store
// drain. Now the (strip,kstep) chunks are software-pipelined with double-
// buffered B-fragments: next chunk's loads are issued BEFORE the current
// strip's stores, so the load wait becomes vmcnt(>=4) and never forces a
// store drain. Full unroll keeps all fragment indices compile-time.

constexpr int D    = 512;
constexpr int KTOT = 121;
constexpr float TAU = 0.07f;

constexpr int GB[5]  = {0, 2, 17, 57, 97};   // group base row in concat [121] layout
constexpr int GK[5]  = {2, 15, 40, 40, 24};  // prototypes per group
constexpr int GD2[5] = {1, 3, 5, 5, 4};      // second attribute cardinality
constexpr int GNA[5] = {1, 2, 2, 2, 2};      // number of attributes
constexpr int KS0[5] = {0, 0, 0, 1, 3};      // first live 32-wide kstep of group
constexpr int KS1[5] = {1, 1, 2, 4, 4};      // one past last live kstep

using f32x4 = __attribute__((ext_vector_type(4))) float;
using s16x8 = __attribute__((ext_vector_type(8))) short;

__device__ __forceinline__ const float* pick(int k,
    const float* P0, const float* P1, const float* P2, const float* P3, const float* P4,
    int* kl) {
  if (k < 2)  { *kl = k;      return P0; }
  if (k < 17) { *kl = k - 2;  return P1; }
  if (k < 57) { *kl = k - 17; return P2; }
  if (k < 97) { *kl = k - 57; return P3; }
  *kl = k - 97; return P4;
}

__device__ __forceinline__ short f2bf(float f) {
  __hip_bfloat16 h = __float2bfloat16(f);   // RTNE
  return *reinterpret_cast<short*>(&h);
}

// ---- merged prep kernel -------------------------------------------------
// Blocks 0..7   (ct): pnbf 16-col slab — compute the 16 prototype-row norms
//                     in-block, then write the 16 fragment-linear s-blocks.
// Blocks 8..647 (c2): one 512-u16 fragment-linear block of mptbf.
// pnbf[(ct*16+s)*512 + lane*8 + j] = Pn[ct*16+(lane&15)][s*32+(lane>>4)*8+j]
// mptbf[(c*4+ks)*512 + lane*8 + j] = Mtilde[ks*32+(lane>>4)*8+j][c*16+(lane&15)]
__global__ __launch_bounds__(256) void prep_all(
    const float* __restrict__ P0, const float* __restrict__ P1,
    const float* __restrict__ P2, const float* __restrict__ P3,
    const float* __restrict__ P4, unsigned short* __restrict__ pnbf,
    unsigned short* __restrict__ mptbf) {
  const int tid = threadIdx.x;
  if (blockIdx.x < 8) {
    const int ct = blockIdx.x;
    __shared__ float lsum[16][17];
    __shared__ float linv[16];
    {
      const int i = tid >> 4, part = tid & 15;
      const int col = ct * 16 + i;
      float s = 0.f;
      if (col < KTOT) {
        int kl; const float* P = pick(col, P0, P1, P2, P3, P4, &kl);
        const float* row = P + (size_t)kl * D + part * 32;
        #pragma unroll
        for (int e = 0; e < 32; ++e) { float v = row[e]; s += v * v; }
      }
      lsum[i][part] = s;
    }
    __syncthreads();
    if (tid < 16) {
      float s = 0.f;
      #pragma unroll
      for (int p = 0; p < 16; ++p) s += lsum[tid][p];
      linv[tid] = 1.f / (sqrtf(s) + 1e-6f);
    }
    __syncthreads();
    for (int s = 0; s < 16; ++s) {
      #pragma unroll
      for (int half = 0; half < 2; ++half) {
        const int e = tid + half * 256;
        const int lane = e >> 3, j = e & 7;
        const int col = ct * 16 + (lane & 15);
        const int k   = s * 32 + (lane >> 4) * 8 + j;
        float v = 0.f;
        if (col < KTOT) {
          int kl; const float* P = pick(col, P0, P1, P2, P3, P4, &kl);
          v = P[(size_t)kl * D + k] * linv[lane & 15];
        }
        pnbf[(size_t)(ct * 16 + s) * 512 + e] = (unsigned short)f2bf(v);
      }
    }
  } else {
    const int c2 = blockIdx.x - 8;           // 0..639
    const int c = c2 >> 2, ks = c2 & 3;
    #pragma unroll
    for (int half = 0; half < 2; ++half) {
      const int e = tid + half * 256;
      const int lane = e >> 3, j = e & 7;
      const int gd = c * 16 + (lane & 15);
      const int k  = ks * 32 + (lane >> 4) * 8 + j;
      const int g = gd >> 9, d = gd & (D - 1);
      float v = 0.f;
      if (k >= GB[g] && k < GB[g] + GK[g]) {
        int kl = k - GB[g];
        const float* P = (g == 0) ? P0 : (g == 1) ? P1 : (g == 2) ? P2 : (g == 3) ? P3 : P4;
        int d2 = GD2[g], na = GNA[g], K = GK[g];
        int a1 = kl / d2, a2 = kl % d2;
        float s = 0.f, m = 0.f;
        for (int jj = 0; jj < K; jj++) {
          float aff;
          if (na == 1) {
            aff = (jj == kl) ? 1.f : 0.f;
          } else {
            int b1 = jj / d2, b2 = jj % d2;
            aff = 0.5f * (float)((a1 == b1) + (a2 == b2));
          }
          s += aff;
          m += aff * P[(size_t)jj * D + d];
        }
        v = m / (s + 1e-6f);
      }
      mptbf[(size_t)c2 * 512 + e] = (unsigned short)f2bf(v);
    }
  }
}

// ---- phase 2 per-group body: chunk-pipelined, store-decoupled -----------
// Flattened chunks c = (strip i, kstep wj), NC = 4*W total. Per chunk:
// issue NEXT chunk's 4 B-loads FIRST, then MFMA current (its loads were
// issued last iteration, before any newer stores -> the compiler's load
// wait tolerates >=4 outstanding newer ops and never forces store drain).
// Strip end: LDS bounce (4x b128) -> 4 rows x 256B nt stores.
template <int G>
__device__ __forceinline__ void phase2_group(
    const s16x8 (&af2)[4], const unsigned short* __restrict__ mptbf,
    float* __restrict__ ob, float* __restrict__ obase, int ch, int lane) {
  constexpr int W  = KS1[G] - KS0[G];
  constexpr int NC = 4 * W;
  const int l15 = lane & 15, hi = lane >> 4;

  s16x8 b[2][4];
  {  // prologue: load chunk 0 (strip 0, ks = KS0)
    const int s0 = G * 8 + ch;
    #pragma unroll
    for (int t = 0; t < 4; ++t)
      b[0][t] = *(const s16x8*)(mptbf +
          (size_t)((s0 * 4 + t) * 4 + KS0[G]) * 512 + lane * 8);
  }

  f32x4 a0 = (f32x4){0.f, 0.f, 0.f, 0.f}, a1 = a0, a2 = a0, a3 = a0;

  #pragma unroll
  for (int c = 0; c < NC; ++c) {             // fully unrolled: all idx static
    const int i  = c / W;
    const int wj = c - i * W;
    const int ks = KS0[G] + wj;

    if (wj == 0) { a0 = a1 = a2 = a3 = (f32x4){0.f, 0.f, 0.f, 0.f}; }

    // prefetch next chunk BEFORE this strip's stores (vmcnt decoupling)
    if (c + 1 < NC) {
      const int i2  = (c + 1) / W;
      const int wj2 = (c + 1) - i2 * W;
      const int s2  = G * 8 + i2 * 2 + ch;
      const int ks2 = KS0[G] + wj2;
      #pragma unroll
      for (int t = 0; t < 4; ++t)
        b[(c + 1) & 1][t] = *(const s16x8*)(mptbf +
            (size_t)((s2 * 4 + t) * 4 + ks2) * 512 + lane * 8);
    }

    const s16x8* bc = b[c & 1];
    a0 = __builtin_amdgcn_mfma_f32_16x16x32_bf16(bc[0], af2[ks], a0, 0, 0, 0);
    a1 = __builtin_amdgcn_mfma_f32_16x16x32_bf16(bc[1], af2[ks], a1, 0, 0, 0);
    a2 = __builtin_amdgcn_mfma_f32_16x16x32_bf16(bc[2], af2[ks], a2, 0, 0, 0);
    a3 = __builtin_amdgcn_mfma_f32_16x16x32_bf16(bc[3], af2[ks], a3, 0, 0, 0);

    if (wj == W - 1) {                       // strip complete: bounce + store
      const int s = G * 8 + i * 2 + ch;
      *(f32x4*)&ob[l15 * 68 +  0 + hi * 4] = a0;
      *(f32x4*)&ob[l15 * 68 + 16 + hi * 4] = a1;
      *(f32x4*)&ob[l15 * 68 + 32 + hi * 4] = a2;
      *(f32x4*)&ob[l15 * 68 + 48 + hi * 4] = a3;
      float* gp = obase + (size_t)s * 64 + l15 * 4;
      #pragma unroll
      for (int r2 = 0; r2 < 4; ++r2) {
        const int row = r2 * 4 + hi;
        f32x4 v = *(const f32x4*)&ob[row * 68 + l15 * 4];
        __builtin_nontemporal_store(v, (f32x4*)(gp + (size_t)row * (5 * D)));
      }
    }
  }
}

// ---- main fused kernel --------------------------------------------------
// 1024 blocks x 256 threads (4 waves); block owns 32 rows. Phase 1: wave
// slab = w&1 (16 rows), ch = w>>1 (64-col half), 16 ksteps x 4 MFMA.
// Phase 2: wave takes 4 strips per group (parity ch), chunk-pipelined.
__global__ __launch_bounds__(256, 4) void fused_main(
    const float* __restrict__ x, const unsigned short* __restrict__ pnbf,
    const unsigned short* __restrict__ mptbf, float* __restrict__ out) {
  // smem: lred[128][33] (16896B) then per-wave 16x68 bounce tiles (17408B).
  __shared__ __align__(16) float smem[4352];
  __shared__ float xsqs[32];
  float (*lred)[33] = (float (*)[33])smem;

  const int tid  = threadIdx.x;
  const int lane = tid & 63;
  const int w    = __builtin_amdgcn_readfirstlane(tid >> 6);
  const int r0   = blockIdx.x * 32;

  const int wr = (w & 1) << 4;   // wave's 16-row slab (block-local)
  const int ch = w >> 1;         // column half / strip parity
  const int ko = (lane >> 4) << 3;

  // ---- phase 1: 16x64 logit tile via MFMA, K = 512 ----
  {
    const int arow = wr + (lane & 15);
    const float* xrow = x + (size_t)(r0 + arow) * D + ko;

    f32x4 acc[4];
    #pragma unroll
    for (int t = 0; t < 4; ++t) acc[t] = (f32x4){0.f, 0.f, 0.f, 0.f};
    float xsq = 0.f;

    #pragma unroll 4
    for (int s = 0; s < 16; ++s) {
      float4 a0 = *(const float4*)(xrow + s * 32);
      float4 a1 = *(const float4*)(xrow + s * 32 + 4);
      xsq += a0.x * a0.x + a0.y * a0.y + a0.z * a0.z + a0.w * a0.w
           + a1.x * a1.x + a1.y * a1.y + a1.z * a1.z + a1.w * a1.w;
      s16x8 af;
      af[0] = f2bf(a0.x); af[1] = f2bf(a0.y); af[2] = f2bf(a0.z); af[3] = f2bf(a0.w);
      af[4] = f2bf(a1.x); af[5] = f2bf(a1.y); af[6] = f2bf(a1.z); af[7] = f2bf(a1.w);
      #pragma unroll
      for (int t = 0; t < 4; ++t) {
        // fragment-linear B: one contiguous 1KB wave load
        s16x8 bfv = *(const s16x8*)(pnbf + (size_t)(((ch << 2) + t) * 16 + s) * 512 + lane * 8);
        acc[t] = __builtin_amdgcn_mfma_f32_16x16x32_bf16(af, bfv, acc[t], 0, 0, 0);
      }
    }

    // ||x||^2: lanes {l, l^16, l^32, l^48} share the same A-row
    xsq += __shfl_xor(xsq, 16);
    xsq += __shfl_xor(xsq, 32);
    if (ch == 0 && lane < 16) xsqs[wr + lane] = xsq;

    // dump C-frags: col = lane&15, row = (lane>>4)*4 + j
    const int drow = wr + ((lane >> 4) << 2);
    #pragma unroll
    for (int t = 0; t < 4; ++t) {
      const int col = (ch << 6) + (t << 4) + (lane & 15);
      #pragma unroll
      for (int j = 0; j < 4; ++j) lred[col][drow + j] = acc[t][j];
    }
  }
  __syncthreads();

  // ---- softmax (lane = row, 32 rows): w0 -> g0,g4; w1 -> g1; w2 -> g2;
  // w3 -> g3 (3-pass in LDS) ----
  if (lane < 32) {
    const float scale = 1.f / ((sqrtf(xsqs[lane]) + 1e-6f) * TAU);
    const int gfirst = (w == 0) ? 0 : w;
    const int glast  = (w == 0) ? 4 : w;     // w0 does 0 then 4
    for (int g = gfirst; g <= glast; g += (w == 0) ? 4 : 1) {
      float mx = -1e30f;
      for (int kk = 0; kk < GK[g]; ++kk)
        mx = fmaxf(mx, lred[GB[g] + kk][lane]);
      float E = 0.f;
      for (int kk = 0; kk < GK[g]; ++kk) {
        float e = __expf((lred[GB[g] + kk][lane] - mx) * scale);
        lred[GB[g] + kk][lane] = e;
        E += e;
      }
      const float inv = 1.f / E;
      for (int kk = 0; kk < GK[g]; ++kk) lred[GB[g] + kk][lane] *= inv;
    }
  }
  __syncthreads();

  // ---- A-frags for phase 2 (c as MFMA B-operand; lred still live) ----
  s16x8 af2[4];
  {
    const int ar = wr + (lane & 15);
    #pragma unroll
    for (int s = 0; s < 4; ++s) {
      const int kbase = s * 32 + ko;
      s16x8 f;
      #pragma unroll
      for (int j = 0; j < 8; ++j) f[j] = f2bf(lred[kbase + j][ar]);
      af2[s] = f;
    }
  }
  __syncthreads();   // lred dead; smem becomes per-wave store-bounce tiles

  // ---- phase 2: out[32 x 2560] = C @ Btilde, chunk-pipelined strips ----
  {
    float* ob    = smem + w * (16 * 68);                  // per-wave 16x68 tile
    float* obase = out + (size_t)(r0 + wr) * (5 * D);     // slab's global base

    phase2_group<0>(af2, mptbf, ob, obase, ch, lane);
    phase2_group<1>(af2, mptbf, ob, obase, ch, lane);
    phase2_group<2>(af2, mptbf, ob, obase, ch, lane);
    phase2_group<3>(af2, mptbf, ob, obase, ch, lane);
    phase2_group<4>(af2, mptbf, ob, obase, ch, lane);
  }
}

extern "C" void kernel_launch(void* const* d_in, const int* in_sizes, int n_in,
                              void* d_out, int out_size, void* d_ws, size_t ws_size,
                              hipStream_t stream) {
  const float* x  = (const float*)d_in[0];
  const float* P0 = (const float*)d_in[1];  // gender [2,512]
  const float* P1 = (const float*)d_in[2];  // hair   [15,512]
  const float* P2 = (const float*)d_in[3];  // top    [40,512]
  const float* P3 = (const float*)d_in[4];  // pants  [40,512]
  const float* P4 = (const float*)d_in[5];  // shoes  [24,512]
  float* out = (float*)d_out;

  unsigned short* pnbf  = (unsigned short*)d_ws;       // 128*512  u16 = 128 KiB
  unsigned short* mptbf = pnbf + 128 * 512;            // 640*512  u16 = 640 KiB

  prep_all<<<dim3(648), dim3(256), 0, stream>>>(P0, P1, P2, P3, P4, pnbf, mptbf);
  fused_main<<<dim3(1024), dim3(256), 0, stream>>>(x, pnbf, mptbf, out);
}